// Round 2
// 303.794 us; speedup vs baseline: 1.0547x; 1.0547x over previous
//
#include <hip/hip_runtime.h>

#define NN 200000
#define DD 256
#define KK 20

typedef float nt_f4 __attribute__((ext_vector_type(4)));

// ---------------------------------------------------------------------------
// K1: streaming pass. Grid = nb blocks x 256 threads (4 waves).
// Wave w of block b handles rows base + 4*s + w, s = 0..chunk/4-1.
// Each wave's 64 lanes cover the full 256-col row via float4 (lane -> cols
// 4*lane..4*lane+3). 80 fp32 accumulators/lane (20 k x 4 cols).
// Explicit 3-buffer software pipeline, prefetch distance 2: Z row (1KB/wave
// global_load_dwordx4, NON-TEMPORAL via ext_vector_type — HIP float4 is a
// class and the builtin rejects it; Z is 204.8 MB streamed once, keep it
// out of L2 so P rows / partials stay resident) and P row (wave-uniform via
// readfirstlane -> scalar path, cached) are loaded 2 stages ahead of use.
// __launch_bounds__(256,2) keeps the VGPR budget big enough (~170) that the
// pipeline lives in registers.
// Block 0 thread 0 also zeroes *out: all K1 blocks retire before K2 launches
// (same stream), so this replaces the hipMemsetAsync dispatch.
// ---------------------------------------------------------------------------

#define STAGE_LOAD(s, zv, Q0, Q1, Q2, Q3, Q4)                              \
  {                                                                        \
    int j_ = base + ((s) << 2) + w;                                        \
    if (j_ > NN - 1) j_ = 0; /* clamp: loaded data never consumed */       \
    zv = __builtin_nontemporal_load(                                       \
        (const nt_f4*)(Z + (size_t)j_ * DD + 4 * lane));                   \
    int ru_ = __builtin_amdgcn_readfirstlane(j_);                          \
    const float4* pp_ = (const float4*)(P + (size_t)ru_ * KK);             \
    Q0 = pp_[0]; Q1 = pp_[1]; Q2 = pp_[2]; Q3 = pp_[3]; Q4 = pp_[4];       \
  }

#define STAGE_COMPUTE(zv, Q0, Q1, Q2, Q3, Q4)                              \
  {                                                                        \
    float zz_[4] = {zv.x, zv.y, zv.z, zv.w};                               \
    float pv_[KK] = {Q0.x, Q0.y, Q0.z, Q0.w, Q1.x, Q1.y, Q1.z, Q1.w,       \
                     Q2.x, Q2.y, Q2.z, Q2.w, Q3.x, Q3.y, Q3.z, Q3.w,       \
                     Q4.x, Q4.y, Q4.z, Q4.w};                              \
    t1 += zz_[0] * zz_[0] + zz_[1] * zz_[1];                               \
    t1 += zz_[2] * zz_[2] + zz_[3] * zz_[3];                               \
    _Pragma("unroll") for (int k_ = 0; k_ < KK; ++k_) {                    \
      _Pragma("unroll") for (int c_ = 0; c_ < 4; ++c_)                     \
          acc[k_][c_] += zz_[c_] * pv_[k_];                                \
    }                                                                      \
  }

__global__ __launch_bounds__(256, 2) void egac_main(
    const float* __restrict__ Z, const float* __restrict__ P,
    float* __restrict__ ztp_part, float* __restrict__ t1_part,
    float* __restrict__ out, int chunk) {
  const int t = threadIdx.x;
  const int lane = t & 63;
  const int w = t >> 6;  // wave id 0..3 (wave-uniform)
  const int b = blockIdx.x;
  const int base = b * chunk;       // launcher guarantees nb*chunk == NN
  const int nst = chunk >> 2;       // stages per wave; (nst-2) % 3 == 0

  // Replace the dedicated 4-byte memset dispatch: K2 only runs after every
  // K1 block has retired (stream order), so any K1 block may zero the output.
  if (b == 0 && t == 0) *out = 0.f;

  float acc[KK][4];
#pragma unroll
  for (int k = 0; k < KK; ++k)
#pragma unroll
    for (int c = 0; c < 4; ++c) acc[k][c] = 0.f;
  float t1 = 0.f;

  nt_f4 zA, zB, zC;
  float4 A0, A1, A2, A3, A4;
  float4 B0, B1, B2, B3, B4;
  float4 C0, C1, C2, C3, C4;

  STAGE_LOAD(0, zA, A0, A1, A2, A3, A4);
  STAGE_LOAD(1, zB, B0, B1, B2, B3, B4);

  int s = 0;
  const int m_end = (nst - 2) / 3;
  for (int m = 0; m < m_end; ++m) {
    STAGE_LOAD(s + 2, zC, C0, C1, C2, C3, C4);
    STAGE_COMPUTE(zA, A0, A1, A2, A3, A4);
    STAGE_LOAD(s + 3, zA, A0, A1, A2, A3, A4);
    STAGE_COMPUTE(zB, B0, B1, B2, B3, B4);
    STAGE_LOAD(s + 4, zB, B0, B1, B2, B3, B4);
    STAGE_COMPUTE(zC, C0, C1, C2, C3, C4);
    s += 3;
  }
  STAGE_COMPUTE(zA, A0, A1, A2, A3, A4);
  STAGE_COMPUTE(zB, B0, B1, B2, B3, B4);

  // ---- intra-block reduction over the 4 waves ----
  __shared__ float red[KK][DD];
  __shared__ float wsum[4];
  for (int ph = 0; ph < 4; ++ph) {
    if (w == ph) {
      if (ph == 0) {
#pragma unroll
        for (int k = 0; k < KK; ++k)
          ((float4*)&red[k][0])[lane] =
              make_float4(acc[k][0], acc[k][1], acc[k][2], acc[k][3]);
      } else {
#pragma unroll
        for (int k = 0; k < KK; ++k) {
          float4 r = ((float4*)&red[k][0])[lane];
          r.x += acc[k][0]; r.y += acc[k][1];
          r.z += acc[k][2]; r.w += acc[k][3];
          ((float4*)&red[k][0])[lane] = r;
        }
      }
    }
    __syncthreads();
  }

  // term1: per-wave shuffle reduce, 4 wave leaders -> LDS
#pragma unroll
  for (int off = 32; off > 0; off >>= 1) t1 += __shfl_xor(t1, off, 64);
  if (lane == 0) wsum[w] = t1;
  __syncthreads();

  // coalesced float4 write-out of the 5120-float block partial
  float4* dst = (float4*)(ztp_part + (size_t)b * (KK * DD));
  const float4* src = (const float4*)&red[0][0];
#pragma unroll
  for (int i = 0; i < (KK * DD) / (4 * 256); ++i)
    dst[i * 256 + t] = src[i * 256 + t];
  if (t == 0) t1_part[b] = wsum[0] + wsum[1] + wsum[2] + wsum[3];
}

// ---------------------------------------------------------------------------
// K2: cross-block reduction + final scalar. Grid = 160 blocks x 512 threads.
// Block handles 32 entries of the 5120-entry ztp; thread = (psub = t>>5,
// e_local = t&31); thread sums partials p = psub, psub+16, ... (generic nb),
// LDS tree over 16 psubs, square-sum -> one atomicAdd per block.
// Block 0 also folds in term1. out zeroed by K1 (stream-ordered before us).
// ---------------------------------------------------------------------------
__global__ __launch_bounds__(512) void egac_reduce(
    const float* __restrict__ ztp_part, const float* __restrict__ t1_part,
    float* __restrict__ out, int nb) {
  __shared__ float red[16][32];
  const int t = threadIdx.x;
  const int el = t & 31;
  const int ps = t >> 5;  // 0..15
  const int e = blockIdx.x * 32 + el;

  float s = 0.f;
  for (int p = ps; p < nb; p += 16) s += ztp_part[(size_t)p * (KK * DD) + e];
  red[ps][el] = s;
  __syncthreads();
  for (int sh = 8; sh >= 1; sh >>= 1) {
    if (ps < sh) red[ps][el] += red[ps + sh][el];
    __syncthreads();
  }
  if (t == 0) {
    float ssq = 0.f;
#pragma unroll
    for (int i = 0; i < 32; ++i) {
      float v = red[0][i];
      ssq += v * v;
    }
    atomicAdd(out, -ssq);  // term2 enters negatively
  }

  if (blockIdx.x == 0) {
    float v = 0.f;
    for (int i = t; i < nb; i += 512) v += t1_part[i];
#pragma unroll
    for (int off = 32; off > 0; off >>= 1) v += __shfl_xor(v, off, 64);
    __shared__ float w2[8];
    if ((t & 63) == 0) w2[t >> 6] = v;
    __syncthreads();
    if (t == 0) {
      float tt = 0.f;
#pragma unroll
      for (int i = 0; i < 8; ++i) tt += w2[i];
      atomicAdd(out, tt);  // + term1
    }
  }
}

extern "C" void kernel_launch(void* const* d_in, const int* in_sizes, int n_in,
                              void* d_out, int out_size, void* d_ws,
                              size_t ws_size, hipStream_t stream) {
  const float* Z = (const float*)d_in[0];
  const float* P = (const float*)d_in[1];
  float* out = (float*)d_out;

  // nb * chunk == NN exactly; chunk/4 stages with (nst-2) % 3 == 0.
  // nb=1000 -> chunk=200 (nst=50); fallback nb=250 -> chunk=800 (nst=200).
  int nb = 1000;
  size_t need = (size_t)nb * (KK * DD) * sizeof(float) + (size_t)nb * sizeof(float);
  if (ws_size < need) nb = 250;
  int chunk = NN / nb;

  float* ztp_part = (float*)d_ws;
  float* t1_part = (float*)d_ws + (size_t)nb * KK * DD;

  // No hipMemsetAsync: egac_main block 0 zeroes *out before egac_reduce runs.
  egac_main<<<nb, 256, 0, stream>>>(Z, P, ztp_part, t1_part, out, chunk);
  egac_reduce<<<160, 512, 0, stream>>>(ztp_part, t1_part, out, nb);
}